// Round 8
// baseline (1809.674 us; speedup 1.0000x reference)
//
#include <hip/hip_runtime.h>

#define HD 64
#define GB 16            // batch rows per block (MFMA M dimension)
#define L2E 1.4426950408889634f

typedef _Float16 h8 __attribute__((ext_vector_type(8)));   // MFMA A/B frag (4 VGPRs)
typedef float    f4 __attribute__((ext_vector_type(4)));   // MFMA C/D frag

__device__ __forceinline__ float fexp2(float x) { return __builtin_amdgcn_exp2f(x); }
__device__ __forceinline__ float frcp(float x)  { return __builtin_amdgcn_rcpf(x); }
__device__ __forceinline__ float ftanh_fast(float x) {
    return 1.f - 2.f * frcp(fexp2(2.f * L2E * x) + 1.f);
}
__device__ __forceinline__ float fsig(float x) {
    return frcp(fexp2(-L2E * x) + 1.f);
}

__device__ __forceinline__ f4 MF(h8 a, h8 b, f4 c) {
    return __builtin_amdgcn_mfma_f32_16x16x32_f16(a, b, c, 0, 0, 0);
}

// Stage one B-fragment: W row-major [256][64] f32; B-frag for (gate-row range,
// k-tile KO): lane holds col=(lane&15) of the tile, k = KO + 8*(lane>>4)+e.
__device__ __forceinline__ h8 stg(const float* W, int gr, int ko, int lane) {
    const float* p = W + (size_t)gr * HD + ko + 8 * (lane >> 4);
    float4 u = *(const float4*)p;
    float4 v = *(const float4*)(p + 4);
    return h8{(_Float16)u.x, (_Float16)u.y, (_Float16)u.z, (_Float16)u.w,
              (_Float16)v.x, (_Float16)v.y, (_Float16)v.z, (_Float16)v.w};
}

// R7 post-mortem: per-step weight re-reads are the wall on every memory tier
// (regs: compiler denies >~64 resident, R2-R6; LDS: 192 ds_read/step on the
// shared DS pipe = ~1400cy, R7). Fix the STRUCTURE: amortize weights over
// GB=16 batch rows with MFMA. gates[16,256] = h[16,64] @ W^T as 16x16x32
// MFMAs; weights = B-frags, 32 VGPRs/wave (no spill pressure), read ONCE.
//
// 12 waves, one block per 16 batch:
//   w0-3 : layer-0 recurrence. Wave w owns cols j=16w+(lane&15) of ALL 4
//          gates (N-tiles {g*4... rows 64g+16w..+15}) -> per lane: i,f,g,o of
//          hidden unit j for 4 batch rows (C/D: col=lane&15, row=(lane>>4)*4
//          +reg, m89-verified) -> LSTM update is lane-local VALU.
//   w4-7 : layer-1 xproj (lag 1); wave 4 also computes the output head (lag 3).
//   w8-11: layer-1 recurrence (lag 2).
// Rings double-buffered by step parity: ALL reads use slot (i+1)&1, all
// writes slot i&1 (except L1's xp read, slot i&1, written by XP at i-1; XP
// at i writes (i+1)&1 -> no race). ONE barrier per step.
// A-frags: lane reads h[lane&15 (batch)][k=8*(lane>>4)..+7] -> ds_read_b128;
// ring rows padded to 72 f16 (144B) to break the 128B-stride bank conflict.
__global__ __launch_bounds__(768)
void lstm2_kernel(const float* __restrict__ x,     // [B,T]
                  const float* __restrict__ h0in,  // [2,B,HD]
                  const float* __restrict__ c0in,  // [2,B,HD]
                  const float* __restrict__ Wih0,  // [4H,1]
                  const float* __restrict__ Whh0,  // [4H,HD]
                  const float* __restrict__ bih0,
                  const float* __restrict__ bhh0,
                  const float* __restrict__ Wih1,  // [4H,HD]
                  const float* __restrict__ Whh1,  // [4H,HD]
                  const float* __restrict__ bih1,
                  const float* __restrict__ bhh1,
                  const float* __restrict__ Wlin,  // [1,HD]
                  const float* __restrict__ blin,  // [1]
                  float* __restrict__ out,         // [B,T]
                  int B, int T)
{
    const int bbase = blockIdx.x * GB;
    const int tid   = threadIdx.x;
    const int wave  = __builtin_amdgcn_readfirstlane(tid >> 6);
    const int lane  = tid & 63;

    __shared__ __align__(16) _Float16 h0x[2][GB][HD + 8];    // layer-0 h (f16, A-frag layout)
    __shared__ __align__(16) _Float16 h1x[2][GB][HD + 8];    // layer-1 h (f16)
    __shared__ __align__(16) float    h1f32[2][GB][HD + 4];  // layer-1 h (f32, head)
    __shared__ __align__(16) float    xp[2][256][20];        // layer-1 xproj (f32, 80B rows)
    // Occupancy limiter (R4 finding): total static LDS 82080B > 81920 ->
    // compile-time 1 WG/CU -> 3 waves/EU target -> 168-VGPR budget, so the
    // 32-VGPR weight frags + 16 acc stay register-resident.
    __shared__ float ldspad[5800];

    // ---- zero-init ALL LDS (launch-history independence) ----
    {
        _Float16* z0 = &h0x[0][0][0];
        for (int q = tid; q < 2 * GB * (HD + 8); q += 768) z0[q] = (_Float16)0.f;
        _Float16* z1 = &h1x[0][0][0];
        for (int q = tid; q < 2 * GB * (HD + 8); q += 768) z1[q] = (_Float16)0.f;
        float* z2 = &h1f32[0][0][0];
        for (int q = tid; q < 2 * GB * (HD + 4); q += 768) z2[q] = 0.f;
        float* z3 = &xp[0][0][0];
        for (int q = tid; q < 2 * 256 * 20; q += 768) z3[q] = 0.f;
        for (int q = tid; q < 5800; q += 768) ldspad[q] = 0.f;
    }
    __syncthreads();
    { float pv = ldspad[tid]; asm volatile("" :: "v"(pv)); }  // keep pad live

    // ---- stage initial h into slot 1 (read slot of iteration 0) ----
    for (int q = tid; q < GB * HD; q += 768) {
        const int bt = q >> 6, jj = q & 63;
        h0x[1][bt][jj] = (_Float16)h0in[(size_t)(bbase + bt) * HD + jj];
        h1x[1][bt][jj] = (_Float16)h0in[(size_t)B * HD + (size_t)(bbase + bt) * HD + jj];
    }
    __syncthreads();

    const int grp = lane >> 4;                 // 4-row batch group

    if (wave < 4) {
        // ================= layer-0 recurrence (t = i) =================
        const int j = 16 * wave + (lane & 15);             // hidden unit
        const h8 wA0 = stg(Whh0, j,        0, lane), wA1 = stg(Whh0, j,       32, lane);
        const h8 wB0 = stg(Whh0, 64 + j,   0, lane), wB1 = stg(Whh0, 64 + j,  32, lane);
        const h8 wC0 = stg(Whh0, 128 + j,  0, lane), wC1 = stg(Whh0, 128 + j, 32, lane);
        const h8 wD0 = stg(Whh0, 192 + j,  0, lane), wD1 = stg(Whh0, 192 + j, 32, lane);
        const float bA = bih0[j]       + bhh0[j];
        const float bB = bih0[64 + j]  + bhh0[64 + j];
        const float bC = bih0[128 + j] + bhh0[128 + j];
        const float bD = bih0[192 + j] + bhh0[192 + j];
        const float wxA = Wih0[j],       wxB = Wih0[64 + j];
        const float wxC = Wih0[128 + j], wxD = Wih0[192 + j];
        float cst0 = c0in[(size_t)(bbase + 4 * grp + 0) * HD + j];
        float cst1 = c0in[(size_t)(bbase + 4 * grp + 1) * HD + j];
        float cst2 = c0in[(size_t)(bbase + 4 * grp + 2) * HD + j];
        float cst3 = c0in[(size_t)(bbase + 4 * grp + 3) * HD + j];
        const float* xb = x + (size_t)(bbase + 4 * grp) * T;
        float xc0 = xb[0], xc1 = xb[T], xc2 = xb[2 * (size_t)T], xc3 = xb[3 * (size_t)T];

        for (int i = 0; i <= T + 2; ++i) {
            const int sl = (i + 1) & 1, wsl = i & 1;
            if (i < T) {
                h8 A0 = *(const h8*)&h0x[sl][lane & 15][8 * grp];
                h8 A1 = *(const h8*)&h0x[sl][lane & 15][32 + 8 * grp];
                f4 aA = {fmaf(wxA, xc0, bA), fmaf(wxA, xc1, bA), fmaf(wxA, xc2, bA), fmaf(wxA, xc3, bA)};
                f4 aB = {fmaf(wxB, xc0, bB), fmaf(wxB, xc1, bB), fmaf(wxB, xc2, bB), fmaf(wxB, xc3, bB)};
                f4 aC = {fmaf(wxC, xc0, bC), fmaf(wxC, xc1, bC), fmaf(wxC, xc2, bC), fmaf(wxC, xc3, bC)};
                f4 aD = {fmaf(wxD, xc0, bD), fmaf(wxD, xc1, bD), fmaf(wxD, xc2, bD), fmaf(wxD, xc3, bD)};
                float nx0 = xc0, nx1 = xc1, nx2 = xc2, nx3 = xc3;
                if (i + 1 < T) {                       // prefetch next x
                    nx0 = xb[i + 1]; nx1 = xb[(size_t)T + i + 1];
                    nx2 = xb[2 * (size_t)T + i + 1]; nx3 = xb[3 * (size_t)T + i + 1];
                }
                aA = MF(A0, wA0, aA); aA = MF(A1, wA1, aA);
                aB = MF(A0, wB0, aB); aB = MF(A1, wB1, aB);
                aC = MF(A0, wC0, aC); aC = MF(A1, wC1, aC);
                aD = MF(A0, wD0, aD); aD = MF(A1, wD1, aD);
#define ACT0_ROW(R) do { \
                float iv = fsig(aA[R]); float fv = fsig(aB[R]); \
                float gv = ftanh_fast(aC[R]); float ov = fsig(aD[R]); \
                cst##R = fmaf(fv, cst##R, iv * gv); \
                float hh = ov * ftanh_fast(cst##R); \
                h0x[wsl][4 * grp + R][j] = (_Float16)hh; } while (0)
                ACT0_ROW(0); ACT0_ROW(1); ACT0_ROW(2); ACT0_ROW(3);
                xc0 = nx0; xc1 = nx1; xc2 = nx2; xc3 = nx3;
            }
            __syncthreads();
        }
    } else if (wave < 8) {
        // ============ layer-1 xproj (t = i-1) + head on wave 4 (t = i-3) ============
        const int w2 = wave - 4;
        const int j2 = 16 * w2 + (lane & 15);
        const h8 wA0 = stg(Wih1, j2,        0, lane), wA1 = stg(Wih1, j2,       32, lane);
        const h8 wB0 = stg(Wih1, 64 + j2,   0, lane), wB1 = stg(Wih1, 64 + j2,  32, lane);
        const h8 wC0 = stg(Wih1, 128 + j2,  0, lane), wC1 = stg(Wih1, 128 + j2, 32, lane);
        const h8 wD0 = stg(Wih1, 192 + j2,  0, lane), wD1 = stg(Wih1, 192 + j2, 32, lane);
        const float bA = bih1[j2]       + bhh1[j2];
        const float bB = bih1[64 + j2]  + bhh1[64 + j2];
        const float bC = bih1[128 + j2] + bhh1[128 + j2];
        const float bD = bih1[192 + j2] + bhh1[192 + j2];
        // head constants (wave 4 only; harmless elsewhere)
        const int hq = lane & 3, hbr = lane >> 2;
        const float4 wl0 = *(const float4*)(Wlin + 16 * hq);
        const float4 wl1 = *(const float4*)(Wlin + 16 * hq + 4);
        const float4 wl2 = *(const float4*)(Wlin + 16 * hq + 8);
        const float4 wl3 = *(const float4*)(Wlin + 16 * hq + 12);
        const float blin0 = blin[0];

        for (int i = 0; i <= T + 2; ++i) {
            const int sl = (i + 1) & 1;
            if (i >= 1 && i <= T) {
                h8 A0 = *(const h8*)&h0x[sl][lane & 15][8 * grp];
                h8 A1 = *(const h8*)&h0x[sl][lane & 15][32 + 8 * grp];
                f4 aA = {bA, bA, bA, bA};
                f4 aB = {bB, bB, bB, bB};
                f4 aC = {bC, bC, bC, bC};
                f4 aD = {bD, bD, bD, bD};
                aA = MF(A0, wA0, aA); aA = MF(A1, wA1, aA);
                aB = MF(A0, wB0, aB); aB = MF(A1, wB1, aB);
                aC = MF(A0, wC0, aC); aC = MF(A1, wC1, aC);
                aD = MF(A0, wD0, aD); aD = MF(A1, wD1, aD);
                *(f4*)&xp[sl][j2][4 * grp]        = aA;
                *(f4*)&xp[sl][64 + j2][4 * grp]   = aB;
                *(f4*)&xp[sl][128 + j2][4 * grp]  = aC;
                *(f4*)&xp[sl][192 + j2][4 * grp]  = aD;
            }
            if (w2 == 0 && i >= 3) {                   // output head, t = i-3
                const float4* hp4 = (const float4*)&h1f32[sl][hbr][16 * hq];
                float4 hA = hp4[0], hB = hp4[1], hC = hp4[2], hD = hp4[3];
                float p = hA.x * wl0.x + hA.y * wl0.y + hA.z * wl0.z + hA.w * wl0.w;
                p = fmaf(hB.x, wl1.x, fmaf(hB.y, wl1.y, fmaf(hB.z, wl1.z, fmaf(hB.w, wl1.w, p))));
                p = fmaf(hC.x, wl2.x, fmaf(hC.y, wl2.y, fmaf(hC.z, wl2.z, fmaf(hC.w, wl2.w, p))));
                p = fmaf(hD.x, wl3.x, fmaf(hD.y, wl3.y, fmaf(hD.z, wl3.z, fmaf(hD.w, wl3.w, p))));
                p += __shfl_xor(p, 1, 64);
                p += __shfl_xor(p, 2, 64);
                if (hq == 0) out[(size_t)(bbase + hbr) * T + (i - 3)] = p + blin0;
            }
            __syncthreads();
        }
    } else {
        // ================= layer-1 recurrence (t = i-2) =================
        const int w3 = wave - 8;
        const int j3 = 16 * w3 + (lane & 15);
        const h8 wA0 = stg(Whh1, j3,        0, lane), wA1 = stg(Whh1, j3,       32, lane);
        const h8 wB0 = stg(Whh1, 64 + j3,   0, lane), wB1 = stg(Whh1, 64 + j3,  32, lane);
        const h8 wC0 = stg(Whh1, 128 + j3,  0, lane), wC1 = stg(Whh1, 128 + j3, 32, lane);
        const h8 wD0 = stg(Whh1, 192 + j3,  0, lane), wD1 = stg(Whh1, 192 + j3, 32, lane);
        float cst0 = c0in[(size_t)B * HD + (size_t)(bbase + 4 * grp + 0) * HD + j3];
        float cst1 = c0in[(size_t)B * HD + (size_t)(bbase + 4 * grp + 1) * HD + j3];
        float cst2 = c0in[(size_t)B * HD + (size_t)(bbase + 4 * grp + 2) * HD + j3];
        float cst3 = c0in[(size_t)B * HD + (size_t)(bbase + 4 * grp + 3) * HD + j3];

        for (int i = 0; i <= T + 2; ++i) {
            const int sl = (i + 1) & 1, wsl = i & 1;
            if (i >= 2 && i <= T + 1) {
                h8 A0 = *(const h8*)&h1x[sl][lane & 15][8 * grp];
                h8 A1 = *(const h8*)&h1x[sl][lane & 15][32 + 8 * grp];
                f4 aA = *(const f4*)&xp[wsl][j3][4 * grp];         // xp(t), written i-1
                f4 aB = *(const f4*)&xp[wsl][64 + j3][4 * grp];
                f4 aC = *(const f4*)&xp[wsl][128 + j3][4 * grp];
                f4 aD = *(const f4*)&xp[wsl][192 + j3][4 * grp];
                aA = MF(A0, wA0, aA); aA = MF(A1, wA1, aA);
                aB = MF(A0, wB0, aB); aB = MF(A1, wB1, aB);
                aC = MF(A0, wC0, aC); aC = MF(A1, wC1, aC);
                aD = MF(A0, wD0, aD); aD = MF(A1, wD1, aD);
#define ACT1_ROW(R) do { \
                float iv = fsig(aA[R]); float fv = fsig(aB[R]); \
                float gv = ftanh_fast(aC[R]); float ov = fsig(aD[R]); \
                cst##R = fmaf(fv, cst##R, iv * gv); \
                float hh = ov * ftanh_fast(cst##R); \
                h1x[wsl][4 * grp + R][j3] = (_Float16)hh; \
                h1f32[wsl][4 * grp + R][j3] = hh; } while (0)
                ACT1_ROW(0); ACT1_ROW(1); ACT1_ROW(2); ACT1_ROW(3);
            }
            __syncthreads();
        }
    }
}

extern "C" void kernel_launch(void* const* d_in, const int* in_sizes, int n_in,
                              void* d_out, int out_size, void* d_ws, size_t ws_size,
                              hipStream_t stream)
{
    const float* x    = (const float*)d_in[0];
    const float* h0   = (const float*)d_in[1];
    const float* c0   = (const float*)d_in[2];
    const float* Wih0 = (const float*)d_in[3];
    const float* Whh0 = (const float*)d_in[4];
    const float* bih0 = (const float*)d_in[5];
    const float* bhh0 = (const float*)d_in[6];
    const float* Wih1 = (const float*)d_in[7];
    const float* Whh1 = (const float*)d_in[8];
    const float* bih1 = (const float*)d_in[9];
    const float* bhh1 = (const float*)d_in[10];
    const float* Wlin = (const float*)d_in[11];
    const float* blin = (const float*)d_in[12];
    float* out = (float*)d_out;

    const int B = in_sizes[1] / (2 * HD);   // h0 is [2,B,HD]
    const int T = in_sizes[0] / B;          // input is [B,T]

    lstm2_kernel<<<dim3(B / GB), dim3(768), 0, stream>>>(
        x, h0, c0, Wih0, Whh0, bih0, bhh0,
        Wih1, Whh1, bih1, bhh1, Wlin, blin, out, B, T);
}

// Round 9
// 1234.094 us; speedup vs baseline: 1.4664x; 1.4664x over previous
//
#include <hip/hip_runtime.h>

#define HD 64
#define KP 16            // timesteps per phase (one workgroup barrier per phase)
#define NS 32            // ring slots = 2 phases (double buffer)
#define L2E 1.4426950408889634f

typedef _Float16 v2h __attribute__((ext_vector_type(2)));
typedef _Float16 h8  __attribute__((ext_vector_type(8)));

__device__ __forceinline__ float fexp2(float x) { return __builtin_amdgcn_exp2f(x); }
__device__ __forceinline__ float frcp(float x)  { return __builtin_amdgcn_rcpf(x); }
__device__ __forceinline__ float ftanh_fast(float x) {
    return 1.f - 2.f * frcp(fexp2(2.f * L2E * x) + 1.f);
}
__device__ __forceinline__ float fsig(float x) {
    return frcp(fexp2(-L2E * x) + 1.f);
}

#if __has_builtin(__builtin_amdgcn_fdot2)
__device__ __forceinline__ float FDOT2(v2h a, v2h b, float c) {
    return __builtin_amdgcn_fdot2(a, b, c, false);
}
#else
__device__ __forceinline__ float FDOT2(v2h a, v2h b, float c) {
    return fmaf((float)a.x, (float)b.x, fmaf((float)a.y, (float)b.y, c));
}
#endif

// R8 post-mortem: per-step 12-wave __syncthreads costs ~1300-1500 cy
// (R0/R8 both ~1700-1870 cy/step with ~400 cy of work; VALUBusy 4%).
// Proven poisons: (a) per-step barriers; (b) >64 weight-VGPRs/wave ->
// compiler scratch-spills (R1-R6, 140-VGPR cap + 50MB cold-touch); (c) all
// weights via LDS -> DS-pipe serialization ~1400 cy/step (R7).
// This round: R2's validated 4-wave KP-phase pipeline (1 barrier/16 steps)
// + HYBRID weights: k=0..31 of each gate row in 64 named-scalar VGPRs
// (R1/R2's B-waves held 64 without spilling), k=32..63 in LDS f16 with
// 144-byte row pitch: bank-set = (9*row + q) % 8 -> the 64 lanes of each
// ds_read_b128 spread uniformly 8-per-bank (the LDS BW floor, no penalty),
// 16B-aligned. 16 b128/step/hybrid-wave ~= 190 cy vs R7's ~1400.
// Accumulation order is pair-for-pair identical to R2 -> bitwise-identical.

#define CVT2(v)  v2h{(_Float16)v.x, (_Float16)v.y}
#define CVT2H(v) v2h{(_Float16)v.z, (_Float16)v.w}

#define DECL16(P) \
    v2h P##_0,P##_1,P##_2,P##_3,P##_4,P##_5,P##_6,P##_7, \
        P##_8,P##_9,P##_10,P##_11,P##_12,P##_13,P##_14,P##_15

#define DECL32(P) \
    v2h P##_0,P##_1,P##_2,P##_3,P##_4,P##_5,P##_6,P##_7, \
        P##_8,P##_9,P##_10,P##_11,P##_12,P##_13,P##_14,P##_15, \
        P##_16,P##_17,P##_18,P##_19,P##_20,P##_21,P##_22,P##_23, \
        P##_24,P##_25,P##_26,P##_27,P##_28,P##_29,P##_30,P##_31

// First 32 k-elems of one weight row -> 16 named packed-f16 pairs.
#define LOAD16(W, r, P) do { \
    const float4* wp_ = (const float4*)((W) + (size_t)(r) * HD); \
    float4 v_; \
    v_=wp_[0];  P##_0 =CVT2(v_); P##_1 =CVT2H(v_); \
    v_=wp_[1];  P##_2 =CVT2(v_); P##_3 =CVT2H(v_); \
    v_=wp_[2];  P##_4 =CVT2(v_); P##_5 =CVT2H(v_); \
    v_=wp_[3];  P##_6 =CVT2(v_); P##_7 =CVT2H(v_); \
    v_=wp_[4];  P##_8 =CVT2(v_); P##_9 =CVT2H(v_); \
    v_=wp_[5];  P##_10=CVT2(v_); P##_11=CVT2H(v_); \
    v_=wp_[6];  P##_12=CVT2(v_); P##_13=CVT2H(v_); \
    v_=wp_[7];  P##_14=CVT2(v_); P##_15=CVT2H(v_); \
} while (0)

// Full 64-elem row -> 32 pairs (B-waves keep whole rows in registers).
#define LOAD32(W, r, P) do { \
    const float4* wp_ = (const float4*)((W) + (size_t)(r) * HD); \
    float4 v_; \
    v_=wp_[0];  P##_0 =CVT2(v_); P##_1 =CVT2H(v_); \
    v_=wp_[1];  P##_2 =CVT2(v_); P##_3 =CVT2H(v_); \
    v_=wp_[2];  P##_4 =CVT2(v_); P##_5 =CVT2H(v_); \
    v_=wp_[3];  P##_6 =CVT2(v_); P##_7 =CVT2H(v_); \
    v_=wp_[4];  P##_8 =CVT2(v_); P##_9 =CVT2H(v_); \
    v_=wp_[5];  P##_10=CVT2(v_); P##_11=CVT2H(v_); \
    v_=wp_[6];  P##_12=CVT2(v_); P##_13=CVT2H(v_); \
    v_=wp_[7];  P##_14=CVT2(v_); P##_15=CVT2H(v_); \
    v_=wp_[8];  P##_16=CVT2(v_); P##_17=CVT2H(v_); \
    v_=wp_[9];  P##_18=CVT2(v_); P##_19=CVT2H(v_); \
    v_=wp_[10]; P##_20=CVT2(v_); P##_21=CVT2H(v_); \
    v_=wp_[11]; P##_22=CVT2(v_); P##_23=CVT2H(v_); \
    v_=wp_[12]; P##_24=CVT2(v_); P##_25=CVT2H(v_); \
    v_=wp_[13]; P##_26=CVT2(v_); P##_27=CVT2H(v_); \
    v_=wp_[14]; P##_28=CVT2(v_); P##_29=CVT2H(v_); \
    v_=wp_[15]; P##_30=CVT2(v_); P##_31=CVT2H(v_); \
} while (0)

#define DOTG(P, i0, i1, i2, i3, A0, A1) \
    A0 = FDOT2(P##_##i0, p0_, A0); A1 = FDOT2(P##_##i1, p1_, A1); \
    A0 = FDOT2(P##_##i2, p2_, A0); A1 = FDOT2(P##_##i3, p3_, A1);

// Register chunk (q = 0..3): 16 dot2 on one h8 load.
#define DOTBLK4R(HP, q, i0, i1, i2, i3) \
    { h8 hv_ = (HP)[q]; \
      v2h p0_={hv_[0],hv_[1]}, p1_={hv_[2],hv_[3]}; \
      v2h p2_={hv_[4],hv_[5]}, p3_={hv_[6],hv_[7]}; \
      DOTG(wgA, i0,i1,i2,i3, a00,a01) DOTG(wgB, i0,i1,i2,i3, a10,a11) \
      DOTG(wgC, i0,i1,i2,i3, a20,a21) DOTG(wgD, i0,i1,i2,i3, a30,a31) }

// LDS chunk (q = 4..7): 4 ds_read_b128 (one per gate row) + 16 dot2.
#define DOTBLK4L(HP, WL, jj, q) \
    { h8 hv_ = (HP)[q]; \
      v2h p0_={hv_[0],hv_[1]}, p1_={hv_[2],hv_[3]}; \
      v2h p2_={hv_[4],hv_[5]}, p3_={hv_[6],hv_[7]}; \
      h8 wa_ = *(const h8*)&(WL)[(jj)][8*((q)-4)]; \
      h8 wb_ = *(const h8*)&(WL)[64+(jj)][8*((q)-4)]; \
      h8 wc_ = *(const h8*)&(WL)[128+(jj)][8*((q)-4)]; \
      h8 wd_ = *(const h8*)&(WL)[192+(jj)][8*((q)-4)]; \
      a00=FDOT2(v2h{wa_[0],wa_[1]},p0_,a00); a01=FDOT2(v2h{wa_[2],wa_[3]},p1_,a01); \
      a00=FDOT2(v2h{wa_[4],wa_[5]},p2_,a00); a01=FDOT2(v2h{wa_[6],wa_[7]},p3_,a01); \
      a10=FDOT2(v2h{wb_[0],wb_[1]},p0_,a10); a11=FDOT2(v2h{wb_[2],wb_[3]},p1_,a11); \
      a10=FDOT2(v2h{wb_[4],wb_[5]},p2_,a10); a11=FDOT2(v2h{wb_[6],wb_[7]},p3_,a11); \
      a20=FDOT2(v2h{wc_[0],wc_[1]},p0_,a20); a21=FDOT2(v2h{wc_[2],wc_[3]},p1_,a21); \
      a20=FDOT2(v2h{wc_[4],wc_[5]},p2_,a20); a21=FDOT2(v2h{wc_[6],wc_[7]},p3_,a21); \
      a30=FDOT2(v2h{wd_[0],wd_[1]},p0_,a30); a31=FDOT2(v2h{wd_[2],wd_[3]},p1_,a31); \
      a30=FDOT2(v2h{wd_[4],wd_[5]},p2_,a30); a31=FDOT2(v2h{wd_[6],wd_[7]},p3_,a31); }

// 4-gate 64-dot, hybrid: q0..3 from registers, q4..7 from LDS.
#define DOT4H(HP, WL, jj) \
    DOTBLK4R(HP,0, 0,1,2,3)    DOTBLK4R(HP,1, 4,5,6,7) \
    DOTBLK4R(HP,2, 8,9,10,11)  DOTBLK4R(HP,3, 12,13,14,15) \
    DOTBLK4L(HP,WL,jj,4) DOTBLK4L(HP,WL,jj,5) \
    DOTBLK4L(HP,WL,jj,6) DOTBLK4L(HP,WL,jj,7)

// 2-gate chunk (xproj waves, full-register weights).
#define DOTBLK2(HP, q, i0, i1, i2, i3) \
    { h8 hv_ = (HP)[q]; \
      v2h p0_={hv_[0],hv_[1]}, p1_={hv_[2],hv_[3]}; \
      v2h p2_={hv_[4],hv_[5]}, p3_={hv_[6],hv_[7]}; \
      DOTG(wgA, i0,i1,i2,i3, a00,a01) DOTG(wgB, i0,i1,i2,i3, a10,a11) }

#define DOT2N(HP) \
    DOTBLK2(HP,0, 0,1,2,3)     DOTBLK2(HP,1, 4,5,6,7) \
    DOTBLK2(HP,2, 8,9,10,11)   DOTBLK2(HP,3, 12,13,14,15) \
    DOTBLK2(HP,4, 16,17,18,19) DOTBLK2(HP,5, 20,21,22,23) \
    DOTBLK2(HP,6, 24,25,26,27) DOTBLK2(HP,7, 28,29,30,31)

// 4 waves (1 per SIMD), one block per batch element:
//   w0 (A): layer-0 recurrence (hybrid weights; lane = hidden unit).
//   w1 (C): layer-1 recurrence, lag 2 phases (hybrid); stores f32 h for head.
//   w2 (B0): layer-1 xproj gates i,f (full-reg), lag 1 phase.
//   w3 (B1): layer-1 xproj gates g,o (full-reg), lag 1 + output head, lag 3.
// Workgroup barrier once per KP=16 steps; rings double-buffered by phase.
__global__ __launch_bounds__(256)
void lstm2_kernel(const float* __restrict__ x,     // [B,T]
                  const float* __restrict__ h0in,  // [2,B,HD]
                  const float* __restrict__ c0in,  // [2,B,HD]
                  const float* __restrict__ Wih0,  // [4H,1]
                  const float* __restrict__ Whh0,  // [4H,HD]
                  const float* __restrict__ bih0,
                  const float* __restrict__ bhh0,
                  const float* __restrict__ Wih1,  // [4H,HD]
                  const float* __restrict__ Whh1,  // [4H,HD]
                  const float* __restrict__ bih1,
                  const float* __restrict__ bhh1,
                  const float* __restrict__ Wlin,  // [1,HD]
                  const float* __restrict__ blin,  // [1]
                  float* __restrict__ out,         // [B,T]
                  int B, int T)
{
    const int b    = blockIdx.x;
    const int tid  = threadIdx.x;
    const int wave = __builtin_amdgcn_readfirstlane(tid >> 6);  // uniform (SGPR)
    const int lane = tid & 63;

    // Weight second halves (k=32..63), f16. Row pitch 72 f16 = 144 B = 36
    // dwords: bank-set (9r+q)%8 -> 64-lane b128 reads uniform 8/bank (floor).
    __shared__ __align__(16) _Float16 wlA[256][72];          // Whh0 halves
    __shared__ __align__(16) _Float16 wlC[256][72];          // Whh1 halves
    __shared__ __align__(16) _Float16 h0ring[NS][HD];        // layer-0 h (f16)
    __shared__ __align__(16) _Float16 h1ring[NS][HD];        // layer-1 h (f16)
    __shared__ __align__(16) float    h1f32[NS][HD + 4];     // layer-1 h (f32, head)
    __shared__ __align__(16) float    xpring[NS][4][HD];     // layer-1 xproj (f32)
    // Total ~123 KB -> 1 WG/CU.

    // ---- zero-init ring LDS (launch-history independence) ----
    {
        _Float16* z0 = &h0ring[0][0];
        for (int i = tid; i < NS * HD; i += 256) z0[i] = (_Float16)0.f;
        _Float16* z1 = &h1ring[0][0];
        for (int i = tid; i < NS * HD; i += 256) z1[i] = (_Float16)0.f;
        float* z2 = &h1f32[0][0];
        for (int i = tid; i < NS * (HD + 4); i += 256) z2[i] = 0.f;
        float* z3 = &xpring[0][0][0];
        for (int i = tid; i < NS * 4 * HD; i += 256) z3[i] = 0.f;
    }
    // ---- stage weight second halves: thread tid -> row tid of both mats ----
    {
        const int r = tid;
        const float4* a4 = (const float4*)(Whh0 + (size_t)r * HD + 32);
        const float4* c4 = (const float4*)(Whh1 + (size_t)r * HD + 32);
        #pragma unroll
        for (int q0 = 0; q0 < 4; ++q0) {
            float4 u = a4[2 * q0], v = a4[2 * q0 + 1];
            *(h8*)&wlA[r][8 * q0] =
                h8{(_Float16)u.x, (_Float16)u.y, (_Float16)u.z, (_Float16)u.w,
                   (_Float16)v.x, (_Float16)v.y, (_Float16)v.z, (_Float16)v.w};
            float4 u2 = c4[2 * q0], v2 = c4[2 * q0 + 1];
            *(h8*)&wlC[r][8 * q0] =
                h8{(_Float16)u2.x, (_Float16)u2.y, (_Float16)u2.z, (_Float16)u2.w,
                   (_Float16)v2.x, (_Float16)v2.y, (_Float16)v2.z, (_Float16)v2.w};
        }
    }
    __syncthreads();

    const int nphase = (T + KP - 1) / KP + 3;

    if (wave == 0) {
        // ================= A: layer-0 recurrence =================
        DECL16(wgA); DECL16(wgB); DECL16(wgC); DECL16(wgD);
        LOAD16(Whh0, lane,        wgA);
        LOAD16(Whh0, 64 + lane,   wgB);
        LOAD16(Whh0, 128 + lane,  wgC);
        LOAD16(Whh0, 192 + lane,  wgD);
        const float b0 = bih0[lane]       + bhh0[lane];
        const float b1 = bih0[64 + lane]  + bhh0[64 + lane];
        const float b2 = bih0[128 + lane] + bhh0[128 + lane];
        const float b3 = bih0[192 + lane] + bhh0[192 + lane];
        const float wx0 = Wih0[lane];       const float wx1 = Wih0[64 + lane];
        const float wx2 = Wih0[128 + lane]; const float wx3 = Wih0[192 + lane];
        float cst = c0in[b * HD + lane];
        h0ring[NS - 1][lane] = (_Float16)h0in[b * HD + lane];
        const float* xrow = x + (size_t)b * T;
        __syncthreads();

        for (int p = 0; p < nphase; ++p) {
            const int t0 = p * KP;
            if (t0 < T) {
                #pragma unroll 1
                for (int k = 0; k < KP; ++k) {
                    const int t = t0 + k;
                    if (t >= T) break;
                    const float xv = xrow[t];                   // uniform scalar load
                    const h8* hp = (const h8*)h0ring[(t + NS - 1) & (NS - 1)];
                    float a00 = b0, a01 = 0.f, a10 = b1, a11 = 0.f;
                    float a20 = b2, a21 = 0.f, a30 = b3, a31 = 0.f;
                    DOT4H(hp, wlA, lane);
                    const float ai = fmaf(wx0, xv, a00 + a01);
                    const float af = fmaf(wx1, xv, a10 + a11);
                    const float ag = fmaf(wx2, xv, a20 + a21);
                    const float ao = fmaf(wx3, xv, a30 + a31);
                    const float iv = fsig(ai), fv = fsig(af);
                    const float gv = ftanh_fast(ag), ov = fsig(ao);
                    cst = fmaf(fv, cst, iv * gv);
                    const float h = ov * ftanh_fast(cst);
                    h0ring[t & (NS - 1)][lane] = (_Float16)h;   // same-wave roundtrip
                }
            }
            __syncthreads();
        }
    } else if (wave == 1) {
        // ================= C: layer-1 recurrence (lag 2 phases) =================
        DECL16(wgA); DECL16(wgB); DECL16(wgC); DECL16(wgD);
        LOAD16(Whh1, lane,        wgA);
        LOAD16(Whh1, 64 + lane,   wgB);
        LOAD16(Whh1, 128 + lane,  wgC);
        LOAD16(Whh1, 192 + lane,  wgD);
        float cst = c0in[B * HD + b * HD + lane];
        h1ring[NS - 1][lane] = (_Float16)h0in[B * HD + b * HD + lane];
        __syncthreads();

        for (int p = 0; p < nphase; ++p) {
            const int t0 = (p - 2) * KP;
            if (p >= 2 && t0 < T) {
                #pragma unroll 1
                for (int k = 0; k < KP; ++k) {
                    const int t = t0 + k;
                    if (t >= T) break;
                    const int s = t & (NS - 1);
                    const float x0 = xpring[s][0][lane];        // issued early,
                    const float x1 = xpring[s][1][lane];        // consumed after dots
                    const float x2 = xpring[s][2][lane];
                    const float x3 = xpring[s][3][lane];
                    const h8* hp = (const h8*)h1ring[(t + NS - 1) & (NS - 1)];
                    float a00 = 0.f, a01 = 0.f, a10 = 0.f, a11 = 0.f;
                    float a20 = 0.f, a21 = 0.f, a30 = 0.f, a31 = 0.f;
                    DOT4H(hp, wlC, lane);
                    const float ai = x0 + a00 + a01;
                    const float af = x1 + a10 + a11;
                    const float ag = x2 + a20 + a21;
                    const float ao = x3 + a30 + a31;
                    const float iv = fsig(ai), fv = fsig(af);
                    const float gv = ftanh_fast(ag), ov = fsig(ao);
                    cst = fmaf(fv, cst, iv * gv);
                    const float h = ov * ftanh_fast(cst);
                    h1ring[s][lane] = (_Float16)h;
                    h1f32[s][lane]  = h;                        // f32 h for output head
                }
            }
            __syncthreads();
        }
    } else if (wave == 2) {
        // ============ B0: layer-1 xproj, gates i,f (lag 1 phase) ============
        DECL32(wgA); DECL32(wgB);
        LOAD32(Wih1, lane,      wgA);
        LOAD32(Wih1, 64 + lane, wgB);
        const float b0 = bih1[lane]      + bhh1[lane];
        const float b1 = bih1[64 + lane] + bhh1[64 + lane];
        __syncthreads();

        for (int p = 0; p < nphase; ++p) {
            const int t0 = (p - 1) * KP;
            if (p >= 1 && t0 < T) {
                #pragma unroll 1
                for (int k = 0; k < KP; ++k) {
                    const int t = t0 + k;
                    if (t >= T) break;
                    const int s = t & (NS - 1);
                    const h8* hp = (const h8*)h0ring[s];
                    float a00 = b0, a01 = 0.f, a10 = b1, a11 = 0.f;
                    DOT2N(hp);
                    xpring[s][0][lane] = a00 + a01;
                    xpring[s][1][lane] = a10 + a11;
                }
            }
            __syncthreads();
        }
    } else {
        // ====== B1: layer-1 xproj, gates g,o (lag 1) + output head (lag 3) ======
        DECL32(wgA); DECL32(wgB);
        LOAD32(Wih1, 128 + lane, wgA);
        LOAD32(Wih1, 192 + lane, wgB);
        const float b2 = bih1[128 + lane] + bhh1[128 + lane];
        const float b3 = bih1[192 + lane] + bhh1[192 + lane];
        const float blin0 = blin[0];
        __syncthreads();

        for (int p = 0; p < nphase; ++p) {
            const int t0 = (p - 1) * KP;
            if (p >= 1 && t0 < T) {
                #pragma unroll 1
                for (int k = 0; k < KP; ++k) {
                    const int t = t0 + k;
                    if (t >= T) break;
                    const int s = t & (NS - 1);
                    const h8* hp = (const h8*)h0ring[s];
                    float a00 = b2, a01 = 0.f, a10 = b3, a11 = 0.f;
                    DOT2N(hp);
                    xpring[s][2][lane] = a00 + a01;
                    xpring[s][3][lane] = a10 + a11;
                }
            }
            const int t0h = (p - 3) * KP;
            if (p >= 3 && t0h < T && lane < KP) {
                const int t = t0h + lane;
                if (t < T) {
                    const float4* hv4 = (const float4*)h1f32[t & (NS - 1)];
                    const float4* wp  = (const float4*)Wlin;
                    float acc = blin0;
                    #pragma unroll
                    for (int q = 0; q < 16; ++q) {
                        const float4 hv = hv4[q];
                        const float4 wv = wp[q];
                        acc = fmaf(wv.x, hv.x, acc);
                        acc = fmaf(wv.y, hv.y, acc);
                        acc = fmaf(wv.z, hv.z, acc);
                        acc = fmaf(wv.w, hv.w, acc);
                    }
                    out[(size_t)b * T + t] = acc;
                }
            }
            __syncthreads();
        }
    }
}

extern "C" void kernel_launch(void* const* d_in, const int* in_sizes, int n_in,
                              void* d_out, int out_size, void* d_ws, size_t ws_size,
                              hipStream_t stream)
{
    const float* x    = (const float*)d_in[0];
    const float* h0   = (const float*)d_in[1];
    const float* c0   = (const float*)d_in[2];
    const float* Wih0 = (const float*)d_in[3];
    const float* Whh0 = (const float*)d_in[4];
    const float* bih0 = (const float*)d_in[5];
    const float* bhh0 = (const float*)d_in[6];
    const float* Wih1 = (const float*)d_in[7];
    const float* Whh1 = (const float*)d_in[8];
    const float* bih1 = (const float*)d_in[9];
    const float* bhh1 = (const float*)d_in[10];
    const float* Wlin = (const float*)d_in[11];
    const float* blin = (const float*)d_in[12];
    float* out = (float*)d_out;

    const int B = in_sizes[1] / (2 * HD);   // h0 is [2,B,HD]
    const int T = in_sizes[0] / B;          // input is [B,T]

    lstm2_kernel<<<dim3(B), dim3(256), 0, stream>>>(
        x, h0, c0, Wih0, Whh0, bih0, bhh0,
        Wih1, Whh1, bih1, bhh1, Wlin, blin, out, B, T);
}